// Round 3
// baseline (346.439 us; speedup 1.0000x reference)
//
#include <hip/hip_runtime.h>
#include <hip/hip_fp16.h>

#define CH 256
#define HH 96
#define WW 160
#define HW (HH * WW) // 15360

typedef _Float16 h4 __attribute__((ext_vector_type(4)));
typedef float f32x4 __attribute__((ext_vector_type(4)));

__device__ inline unsigned pk2f(float a, float b) {
    return (unsigned)__half_as_ushort(__float2half(a)) |
           ((unsigned)__half_as_ushort(__float2half(b)) << 16);
}

// v7 = v5 + COLUMN-MAJOR tile walk (the only change vs v5).
// Rationale: v4/v5/v6 pinned at 153-163us across occupancy/barrier/MFMA/MLP
// changes -> bound by the L2-miss path. Row-major order makes the ~96
// concurrently-resident blocks per XCD span ~10 y-bands (~4.7 MB/chunk >
// 4 MB L2), so the 6x S-halo redundancy re-fetches from L3 (~700cy).
// Column-major (y fastest, 24 bands x 10 cols) shrinks the resident
// footprint to ~4 tile-columns full-height (~0.9 MB/chunk incl F) -> halo
// re-reads become L2 hits.
__global__ __launch_bounds__(256, 4)
void corr_v7(const float* __restrict__ Fp, const float* __restrict__ Sp,
             float* __restrict__ out) {
    // [buf2][row12][jt2][qq4][n16] : uint2 = 4 halves = 4 channels of group qq
    __shared__ uint2 sS[2 * 12 * 128]; // 24576 B

    const int bid = blockIdx.x;
    const int b   = bid & 7;       // batch-per-XCD swizzle
    const int rem = bid >> 3;      // 0..239
    const int y0  = (rem % 24) * 4;   // y fastest -> resident window is
    const int x0  = (rem / 24) * 16;  // column-compact on each XCD

    const int t    = threadIdx.x;
    const int lane = t & 63;
    const int wv   = t >> 6;
    const int q    = lane >> 4;
    const int n    = lane & 15;

    const float*  Fb  = Fp + (size_t)b * CH * HW;
    const float2* Sb2 = (const float2*)(Sp + (size_t)b * CH * HW);

    // ---- staging lane map: (np, qq, jt)
    const int np = lane & 7;
    const int qq = (lane >> 3) & 3;
    const int jt = (lane >> 5) & 1;
    const int gx = x0 - 4 + jt * 16 + np * 2;
    const bool xok = (gx >= 0) & (gx + 1 < WW);

    bool okv[3];
    int  sOff[3]; // float2-offsets from Sb2
#pragma unroll
    for (int i = 0; i < 3; i++) {
        const int row = i * 4 + wv;
        const int gy  = y0 - 4 + row;
        okv[i] = ((unsigned)gy < HH) & xok;
        sOff[i] = okv[i] ? (qq * 4) * (HW / 2) + gy * (WW / 2) + (gx >> 1) : 0;
    }
    int fOff = (q * 4) * HW + (y0 + wv) * WW + x0 + n;

    // ---- raw prefetch registers: 24 + 4 VGPRs
    float2 rawS[3][4];
    float  rawF[4];
    h4     av;

    auto load_raw = [&]() {
#pragma unroll
        for (int i = 0; i < 3; i++)
#pragma unroll
            for (int j = 0; j < 4; j++)
                rawS[i][j] = Sb2[sOff[i] + j * (HW / 2)];
#pragma unroll
        for (int j = 0; j < 4; j++)
            rawF[j] = Fb[fOff + j * HW];
#pragma unroll
        for (int i = 0; i < 3; i++) sOff[i] += 8 * HW;  // +16 planes (float2 units)
        fOff += 16 * HW;
    };

    const int wrow = jt * 64 + qq * 16 + np * 2;

    auto commit = [&](int wb) {
        h4 a;
#pragma unroll
        for (int j = 0; j < 4; j++) a[j] = (_Float16)rawF[j];
        av = a;
#pragma unroll
        for (int i = 0; i < 3; i++) {
            float ax[4], ay[4];
#pragma unroll
            for (int j = 0; j < 4; j++) {
                ax[j] = okv[i] ? rawS[i][j].x : 0.0f;
                ay[j] = okv[i] ? rawS[i][j].y : 0.0f;
            }
            uint4 v;
            v.x = pk2f(ax[0], ax[1]);  // col gx   : channels 0..3 of group qq
            v.y = pk2f(ax[2], ax[3]);
            v.z = pk2f(ay[0], ay[1]);  // col gx+1
            v.w = pk2f(ay[2], ay[3]);
            *(uint4*)&sS[wb + (i * 4 + wv) * 128 + wrow] = v;
        }
    };

    f32x4 acc[9][2];
#pragma unroll
    for (int dy = 0; dy < 9; dy++) {
        f32x4 z = {0.f, 0.f, 0.f, 0.f};
        acc[dy][0] = z;
        acc[dy][1] = z;
    }

    // ---- prologue: chunk 0 staged to buf0, chunk 1 in flight
    load_raw();
    commit(0);
    load_raw();
    __syncthreads();

#pragma unroll 1
    for (int ch = 0; ch < 16; ch++) {
        const int rb = (ch & 1) ? 1536 : 0;
        const uint2* rp = sS + rb + wv * 128 + q * 16 + n;

        // ---- MFMA on chunk ch (issued before the commit's vmcnt stall)
#pragma unroll
        for (int dy = 0; dy < 9; dy++) {
            h4 b0 = *(const h4*)(rp + dy * 128);        // jt = 0
            h4 b1 = *(const h4*)(rp + dy * 128 + 64);   // jt = 1
            acc[dy][0] = __builtin_amdgcn_mfma_f32_16x16x16f16(av, b0, acc[dy][0], 0, 0, 0);
            acc[dy][1] = __builtin_amdgcn_mfma_f32_16x16x16f16(av, b1, acc[dy][1], 0, 0, 0);
        }

        if (ch < 15) {
            commit(1536 - rb);        // chunk ch+1 -> other buffer
            if (ch < 14) load_raw();  // chunk ch+2 in flight across the barrier
            __syncthreads();          // single barrier per chunk
        }
    }

    // ---- epilogue: D row m=q*4+r, col n; dx+4 = jt*16 + n - m in [0,8].
    const int y = y0 + wv;
#pragma unroll
    for (int r = 0; r < 4; r++) {
        const int m = q * 4 + r;
#pragma unroll
        for (int jtt = 0; jtt < 2; jtt++) {
            const int dxp = jtt * 16 + n - m;
            if (dxp >= 0 && dxp <= 8) {
                float* p = out + ((size_t)(b * 81 + dxp) * HH + y) * WW + x0 + m;
#pragma unroll
                for (int dy = 0; dy < 9; dy++) {
                    p[(size_t)dy * 9 * HW] = acc[dy][jtt][r] * (1.0f / 256.0f);
                }
            }
        }
    }
}

extern "C" void kernel_launch(void* const* d_in, const int* in_sizes, int n_in,
                              void* d_out, int out_size, void* d_ws, size_t ws_size,
                              hipStream_t stream) {
    const float* F = (const float*)d_in[0];
    const float* S = (const float*)d_in[1];
    float* o = (float*)d_out;
    corr_v7<<<dim3(1920), dim3(256), 0, stream>>>(F, S, o);
}

// Round 4
// 333.984 us; speedup vs baseline: 1.0373x; 1.0373x over previous
//
#include <hip/hip_runtime.h>
#include <hip/hip_fp16.h>

#define CH 256
#define HH 96
#define WW 160
#define HW (HH * WW) // 15360

typedef _Float16 h4 __attribute__((ext_vector_type(4)));
typedef float f32x4 __attribute__((ext_vector_type(4)));

__device__ inline unsigned pk2f(float a, float b) {
    return (unsigned)__half_as_ushort(__float2half(a)) |
           ((unsigned)__half_as_ushort(__float2half(b)) << 16);
}

// No-drain workgroup barrier (T3/T4 discipline): __syncthreads() is a
// release fence and forces s_waitcnt vmcnt(0) before s_barrier, draining
// our prefetch loads every chunk (this nullified ALL pipelining in
// v4/v5/v6 -- the 153-163us invariance). The barrier only semantically
// needs LDS ops drained: lgkmcnt(0). Global prefetch loads stay in
// flight across the barrier; their consumption is ordered by the
// compiler's counted vmcnt at first use in commit().
__device__ inline void wg_barrier_nodrain() {
    asm volatile("s_waitcnt lgkmcnt(0)" ::: "memory");
    __builtin_amdgcn_s_barrier();
    asm volatile("" ::: "memory"); // fence ds-op hoisting across barrier
}

// v8 = v5 (row-major walk restored; v7's column-major doubled FETCH via
// partial-line overfetch) + wg_barrier_nodrain instead of __syncthreads.
__global__ __launch_bounds__(256, 4)
void corr_v8(const float* __restrict__ Fp, const float* __restrict__ Sp,
             float* __restrict__ out) {
    // [buf2][row12][jt2][qq4][n16] : uint2 = 4 halves = 4 channels of group qq
    __shared__ uint2 sS[2 * 12 * 128]; // 24576 B

    const int bid = blockIdx.x;
    const int b   = bid & 7;       // batch-per-XCD swizzle
    const int rem = bid >> 3;      // 0..239
    const int y0  = (rem / 10) * 4;
    const int x0  = (rem % 10) * 16;

    const int t    = threadIdx.x;
    const int lane = t & 63;
    const int wv   = t >> 6;
    const int q    = lane >> 4;
    const int n    = lane & 15;

    const float*  Fb  = Fp + (size_t)b * CH * HW;
    const float2* Sb2 = (const float2*)(Sp + (size_t)b * CH * HW);

    // ---- staging lane map: (np, qq, jt)
    const int np = lane & 7;
    const int qq = (lane >> 3) & 3;
    const int jt = (lane >> 5) & 1;
    const int gx = x0 - 4 + jt * 16 + np * 2;
    const bool xok = (gx >= 0) & (gx + 1 < WW);

    bool okv[3];
    int  sOff[3]; // float2-offsets from Sb2
#pragma unroll
    for (int i = 0; i < 3; i++) {
        const int row = i * 4 + wv;
        const int gy  = y0 - 4 + row;
        okv[i] = ((unsigned)gy < HH) & xok;
        sOff[i] = okv[i] ? (qq * 4) * (HW / 2) + gy * (WW / 2) + (gx >> 1) : 0;
    }
    int fOff = (q * 4) * HW + (y0 + wv) * WW + x0 + n;

    // ---- raw prefetch registers: 24 + 4 VGPRs
    float2 rawS[3][4];
    float  rawF[4];
    h4     av;

    auto load_raw = [&]() {
#pragma unroll
        for (int i = 0; i < 3; i++)
#pragma unroll
            for (int j = 0; j < 4; j++)
                rawS[i][j] = Sb2[sOff[i] + j * (HW / 2)];
#pragma unroll
        for (int j = 0; j < 4; j++)
            rawF[j] = Fb[fOff + j * HW];
#pragma unroll
        for (int i = 0; i < 3; i++) sOff[i] += 8 * HW;  // +16 planes (float2 units)
        fOff += 16 * HW;
    };

    const int wrow = jt * 64 + qq * 16 + np * 2;

    auto commit = [&](int wb) {
        h4 a;
#pragma unroll
        for (int j = 0; j < 4; j++) a[j] = (_Float16)rawF[j];
        av = a;
#pragma unroll
        for (int i = 0; i < 3; i++) {
            float ax[4], ay[4];
#pragma unroll
            for (int j = 0; j < 4; j++) {
                ax[j] = okv[i] ? rawS[i][j].x : 0.0f;
                ay[j] = okv[i] ? rawS[i][j].y : 0.0f;
            }
            uint4 v;
            v.x = pk2f(ax[0], ax[1]);  // col gx   : channels 0..3 of group qq
            v.y = pk2f(ax[2], ax[3]);
            v.z = pk2f(ay[0], ay[1]);  // col gx+1
            v.w = pk2f(ay[2], ay[3]);
            *(uint4*)&sS[wb + (i * 4 + wv) * 128 + wrow] = v;
        }
    };

    f32x4 acc[9][2];
#pragma unroll
    for (int dy = 0; dy < 9; dy++) {
        f32x4 z = {0.f, 0.f, 0.f, 0.f};
        acc[dy][0] = z;
        acc[dy][1] = z;
    }

    // ---- prologue: chunk 0 staged to buf0, chunk 1 in flight across barrier
    load_raw();
    commit(0);
    load_raw();
    wg_barrier_nodrain();

#pragma unroll 1
    for (int ch = 0; ch < 16; ch++) {
        const int rb = (ch & 1) ? 1536 : 0;
        const uint2* rp = sS + rb + wv * 128 + q * 16 + n;

        // ---- MFMA on chunk ch
#pragma unroll
        for (int dy = 0; dy < 9; dy++) {
            h4 b0 = *(const h4*)(rp + dy * 128);        // jt = 0
            h4 b1 = *(const h4*)(rp + dy * 128 + 64);   // jt = 1
            acc[dy][0] = __builtin_amdgcn_mfma_f32_16x16x16f16(av, b0, acc[dy][0], 0, 0, 0);
            acc[dy][1] = __builtin_amdgcn_mfma_f32_16x16x16f16(av, b1, acc[dy][1], 0, 0, 0);
        }

        if (ch < 15) {
            commit(1536 - rb);        // chunk ch+1 -> other buffer (counted vmcnt)
            if (ch < 14) load_raw();  // chunk ch+2 stays in flight across barrier
            wg_barrier_nodrain();     // lgkmcnt(0) only -- NO vmcnt drain
        }
    }

    // ---- epilogue: D row m=q*4+r, col n; dx+4 = jt*16 + n - m in [0,8].
    const int y = y0 + wv;
#pragma unroll
    for (int r = 0; r < 4; r++) {
        const int m = q * 4 + r;
#pragma unroll
        for (int jtt = 0; jtt < 2; jtt++) {
            const int dxp = jtt * 16 + n - m;
            if (dxp >= 0 && dxp <= 8) {
                float* p = out + ((size_t)(b * 81 + dxp) * HH + y) * WW + x0 + m;
#pragma unroll
                for (int dy = 0; dy < 9; dy++) {
                    p[(size_t)dy * 9 * HW] = acc[dy][jtt][r] * (1.0f / 256.0f);
                }
            }
        }
    }
}

extern "C" void kernel_launch(void* const* d_in, const int* in_sizes, int n_in,
                              void* d_out, int out_size, void* d_ws, size_t ws_size,
                              hipStream_t stream) {
    const float* F = (const float*)d_in[0];
    const float* S = (const float*)d_in[1];
    float* o = (float*)d_out;
    corr_v8<<<dim3(1920), dim3(256), 0, stream>>>(F, S, o);
}

// Round 5
// 314.284 us; speedup vs baseline: 1.1023x; 1.0627x over previous
//
#include <hip/hip_runtime.h>
#include <hip/hip_fp16.h>

#define CH 256
#define HH 96
#define WW 160
#define HW (HH * WW) // 15360

typedef _Float16 h4 __attribute__((ext_vector_type(4)));
typedef float f32x4 __attribute__((ext_vector_type(4)));

__device__ inline unsigned pk2f(float a, float b) {
    return (unsigned)__half_as_ushort(__float2half(a)) |
           ((unsigned)__half_as_ushort(__float2half(b)) << 16);
}

__device__ inline void wg_barrier_nodrain() {
    asm volatile("s_waitcnt lgkmcnt(0)" ::: "memory");
    __builtin_amdgcn_s_barrier();
    asm volatile("" ::: "memory");
}

// v9: BYTES reduction via taller intra-block tile. Model (fits v4-v8 to 0.3%):
// time = requested vmem bytes / (256 CU x 9.4 B/cyc) -- per-CU long-latency
// service ceiling; L2 reuse across blocks is broken by chunk-phase drift, so
// halo redundancy must be removed INSIDE the block. 8 waves (512 thr), output
// 8x16 per block: S-in 16x32 -> halo redundancy 4x (was 6x at 4x16).
// Requests 880 MB -> 614 MB => predicted ~107 us/dispatch. Occupancy drops
// to 1 block/CU (8 waves) -- irrelevant under the bytes model (per-CU
// outstanding lines stay saturated: ~12 loads in flight x 8 waves).
__global__ __launch_bounds__(512, 2)
void corr_v9(const float* __restrict__ Fp, const float* __restrict__ Sp,
             float* __restrict__ out) {
    // [buf2][row16][jt2][qq4][n16] : uint2 = 4 halves = ch qq*4..+3 at one col
    __shared__ uint2 sS[2 * 16 * 128]; // 32 KB

    const int bid = blockIdx.x;
    const int b   = bid & 7;       // batch-per-XCD swizzle
    const int rem = bid >> 3;      // 0..119
    const int y0  = (rem / 10) * 8;
    const int x0  = (rem % 10) * 16;

    const int t    = threadIdx.x;
    const int lane = t & 63;
    const int wv   = t >> 6;       // 0..7 : wave owns output row y0+wv
    const int q    = lane >> 4;
    const int n    = lane & 15;

    const float*  Fb  = Fp + (size_t)b * CH * HW;
    const float2* Sb2 = (const float2*)(Sp + (size_t)b * CH * HW);

    // ---- staging lane map: (np, qq, jt); S rows r = i*8 + wv, i = 0..1
    const int np = lane & 7;
    const int qq = (lane >> 3) & 3;
    const int jt = (lane >> 5) & 1;
    const int gx = x0 - 4 + jt * 16 + np * 2;
    const bool xok = (gx >= 0) & (gx + 1 < WW);

    bool okv[2];
    int  sOff[2]; // float2-offsets from Sb2
#pragma unroll
    for (int i = 0; i < 2; i++) {
        const int row = i * 8 + wv;          // 0..15
        const int gy  = y0 - 4 + row;        // y0-4 .. y0+11
        okv[i] = ((unsigned)gy < HH) & xok;
        sOff[i] = okv[i] ? (qq * 4) * (HW / 2) + gy * (WW / 2) + (gx >> 1) : 0;
    }
    int fOff = (q * 4) * HW + (y0 + wv) * WW + x0 + n;

    // ---- raw prefetch registers: 16 + 4 VGPRs
    float2 rawS[2][4];
    float  rawF[4];
    h4     av;

    auto load_raw = [&]() {
#pragma unroll
        for (int i = 0; i < 2; i++)
#pragma unroll
            for (int j = 0; j < 4; j++)
                rawS[i][j] = Sb2[sOff[i] + j * (HW / 2)]; // ch = qq*4+j
#pragma unroll
        for (int j = 0; j < 4; j++)
            rawF[j] = Fb[fOff + j * HW];                  // ch = q*4+j
#pragma unroll
        for (int i = 0; i < 2; i++) sOff[i] += 8 * HW;    // +16 planes (float2)
        fOff += 16 * HW;
    };

    const int wrow = jt * 64 + qq * 16 + np * 2;

    auto commit = [&](int wb) {
        h4 a;
#pragma unroll
        for (int j = 0; j < 4; j++) a[j] = (_Float16)rawF[j];
        av = a;
#pragma unroll
        for (int i = 0; i < 2; i++) {
            float ax[4], ay[4];
#pragma unroll
            for (int j = 0; j < 4; j++) {
                ax[j] = okv[i] ? rawS[i][j].x : 0.0f;
                ay[j] = okv[i] ? rawS[i][j].y : 0.0f;
            }
            uint4 v;
            v.x = pk2f(ax[0], ax[1]);  // col gx   : ch qq*4+0..1
            v.y = pk2f(ax[2], ax[3]);  //            ch qq*4+2..3
            v.z = pk2f(ay[0], ay[1]);  // col gx+1
            v.w = pk2f(ay[2], ay[3]);
            *(uint4*)&sS[wb + (i * 8 + wv) * 128 + wrow] = v;
        }
    };

    f32x4 acc[9][2];
#pragma unroll
    for (int dy = 0; dy < 9; dy++) {
        f32x4 z = {0.f, 0.f, 0.f, 0.f};
        acc[dy][0] = z;
        acc[dy][1] = z;
    }

    // ---- prologue: chunk 0 staged to buf0, chunk 1 in flight across barrier
    load_raw();
    commit(0);
    load_raw();
    wg_barrier_nodrain();

#pragma unroll 1
    for (int ch = 0; ch < 16; ch++) {
        const int rb = (ch & 1) ? 2048 : 0;   // 16 rows x 128 uint2 per buffer
        const uint2* rp = sS + rb + wv * 128 + q * 16 + n;

        // ---- MFMA on chunk ch: wave wv reads LDS rows wv+dy (0..15)
#pragma unroll
        for (int dy = 0; dy < 9; dy++) {
            h4 b0 = *(const h4*)(rp + dy * 128);        // jt = 0
            h4 b1 = *(const h4*)(rp + dy * 128 + 64);   // jt = 1
            acc[dy][0] = __builtin_amdgcn_mfma_f32_16x16x16f16(av, b0, acc[dy][0], 0, 0, 0);
            acc[dy][1] = __builtin_amdgcn_mfma_f32_16x16x16f16(av, b1, acc[dy][1], 0, 0, 0);
        }

        if (ch < 15) {
            commit(2048 - rb);        // chunk ch+1 -> other buffer
            if (ch < 14) load_raw();  // chunk ch+2 stays in flight
            wg_barrier_nodrain();     // lgkmcnt(0) only
        }
    }

    // ---- epilogue: D row m=q*4+r, col n; dx+4 = jt*16 + n - m in [0,8].
    const int y = y0 + wv;
#pragma unroll
    for (int r = 0; r < 4; r++) {
        const int m = q * 4 + r;
#pragma unroll
        for (int jtt = 0; jtt < 2; jtt++) {
            const int dxp = jtt * 16 + n - m;
            if (dxp >= 0 && dxp <= 8) {
                float* p = out + ((size_t)(b * 81 + dxp) * HH + y) * WW + x0 + m;
#pragma unroll
                for (int dy = 0; dy < 9; dy++) {
                    p[(size_t)dy * 9 * HW] = acc[dy][jtt][r] * (1.0f / 256.0f);
                }
            }
        }
    }
}

extern "C" void kernel_launch(void* const* d_in, const int* in_sizes, int n_in,
                              void* d_out, int out_size, void* d_ws, size_t ws_size,
                              hipStream_t stream) {
    const float* F = (const float*)d_in[0];
    const float* S = (const float*)d_in[1];
    float* o = (float*)d_out;
    corr_v9<<<dim3(960), dim3(512), 0, stream>>>(F, S, o);
}